// Round 2
// baseline (12619.337 us; speedup 1.0000x reference)
//
#include <hip/hip_runtime.h>
#include <stdint.h>
#include <math.h>

#define B_   64
#define TS_  256
#define TD_  64
#define H_   512
#define E_   512
#define V_   32000
#define G3_  1536

typedef unsigned short u16;
typedef __attribute__((ext_vector_type(8))) short  short8v;
typedef __attribute__((ext_vector_type(4))) float  float4v;

__device__ __forceinline__ u16 f2bf(float x) {
  union { float f; unsigned u; } v; v.f = x;
  unsigned r = v.u + 0x7FFFu + ((v.u >> 16) & 1u);
  return (u16)(r >> 16);
}
__device__ __forceinline__ float bf2f(u16 h) {
  union { unsigned u; float f; } v; v.u = ((unsigned)h) << 16; return v.f;
}
__device__ __forceinline__ float sigm(float x) { return 1.f / (1.f + expf(-x)); }

__device__ __forceinline__ float4v mfma16(short8v a, short8v b, float4v c) {
  return __builtin_amdgcn_mfma_f32_16x16x32_bf16(a, b, c, 0, 0, 0);
}

// ---- device-scope grid barrier: cumulative counter + epoch flag, acquire polls,
// ---- and a timeout valve so a broken barrier can never hang the harness.
__device__ __forceinline__ void gsync(unsigned* cnt, unsigned* flag, unsigned nblk,
                                      unsigned gen, unsigned& dead) {
  __syncthreads();
  if (threadIdx.x == 0 && !dead) {
    __threadfence();  // release: write back this XCD's dirty lines
    unsigned old = __hip_atomic_fetch_add(cnt, 1u, __ATOMIC_ACQ_REL, __HIP_MEMORY_SCOPE_AGENT);
    if (old == gen * nblk - 1u) {
      __hip_atomic_store(flag, gen, __ATOMIC_RELEASE, __HIP_MEMORY_SCOPE_AGENT);
    } else {
      unsigned spins = 0;
      while (__hip_atomic_load(flag, __ATOMIC_ACQUIRE, __HIP_MEMORY_SCOPE_AGENT) < gen) {
        __builtin_amdgcn_s_sleep(4);
        if (++spins > (1u << 24)) { dead = 1u; break; }  // ~10s: bail, don't hang
      }
    }
    __threadfence();  // acquire: invalidate stale lines before data reads
  }
  __syncthreads();
}

// ---------------- embedding gather + bf16 hi/lo split ----------------
__global__ __launch_bounds__(256) void k_embed(const int* __restrict__ seq,
    const float* __restrict__ emb, u16* __restrict__ hi, u16* __restrict__ lo, int total8) {
  int idx = blockIdx.x * 256 + threadIdx.x;
  if (idx >= total8) return;
  int row = idx >> 6;
  int c8  = (idx & 63) << 3;
  const float* src = emb + (size_t)seq[row] * E_ + c8;
  short8v hv, lv;
  #pragma unroll
  for (int i = 0; i < 8; ++i) {
    float x = src[i];
    u16 hb2 = f2bf(x);
    hv[i] = (short)hb2;
    lv[i] = (short)f2bf(x - bf2f(hb2));
  }
  *(short8v*)(hi + (size_t)idx * 8) = hv;
  *(short8v*)(lo + (size_t)idx * 8) = lv;
}

// ---------------- f32 [K][N] -> bf16 [N][K] transpose-convert (optional lo) ----------------
template<bool LO>
__global__ __launch_bounds__(256) void k_transp(const float* __restrict__ src, int ld,
    u16* __restrict__ dh, u16* __restrict__ dl, int K, int N) {
  __shared__ float t[64][65];
  int n0 = blockIdx.x << 6, k0 = blockIdx.y << 6;
  int c = threadIdx.x & 63, r0 = threadIdx.x >> 6;
  #pragma unroll
  for (int i = 0; i < 16; ++i) {
    int r = r0 + (i << 2);
    t[r][c] = src[(size_t)(k0 + r) * ld + n0 + c];
  }
  __syncthreads();
  #pragma unroll
  for (int i = 0; i < 16; ++i) {
    int rr = r0 + (i << 2);
    float v = t[c][rr];
    u16 hb2 = f2bf(v);
    size_t o = (size_t)(n0 + rr) * K + k0 + c;
    dh[o] = hb2;
    if (LO) dl[o] = f2bf(v - bf2f(hb2));
  }
}

__global__ __launch_bounds__(256) void k_cvt(const float* __restrict__ s, u16* __restrict__ d, int n) {
  int i = blockIdx.x * 256 + threadIdx.x;
  if (i < n) d[i] = f2bf(s[i]);
}

// ---------------- bf16 MFMA GEMM: C[M,N] = A[M,K] @ B^T (+bias) ----------------
// B either bf16 [N][K] (optionally hi/lo split with A) or f32 [K][N] on-the-fly (BF32N).
// 128x128 tile, BK=32, 4 waves (2x2), 4x4 16x16 frags/wave, XOR-swizzled 16B chunks.
__device__ __forceinline__ int swzA(int row, int q) {  // ushort offset within [128][32] tile
  return (row << 5) + ((q ^ ((row >> 1) & 3)) << 3);
}

template<bool SPLIT, bool BF32N, bool BIAS, bool OBF>
__global__ __launch_bounds__(256, 2) void k_gemm(
    const u16* __restrict__ Ah, const u16* __restrict__ Al,
    const u16* __restrict__ Bh, const u16* __restrict__ Bl,
    const float* __restrict__ Bf,
    float* __restrict__ C, u16* __restrict__ Cb, const float* __restrict__ bias,
    int M, int N, int K)
{
  __shared__ u16 sA[4096], sB[4096];
  __shared__ u16 sA2[SPLIT ? 4096 : 16], sB2[SPLIT ? 4096 : 16];
  const int tid = threadIdx.x;
  const int ln = tid & 63, wv = tid >> 6;
  const int wr = wv >> 1, wc = wv & 1;
  const int m0 = blockIdx.y << 7, n0 = blockIdx.x << 7;
  const int lm = ln & 15, lq = ln >> 4;
  const float4v zf = {0.f, 0.f, 0.f, 0.f};

  float4v acc[4][4];
  #pragma unroll
  for (int i = 0; i < 4; ++i)
    #pragma unroll
    for (int j = 0; j < 4; ++j) acc[i][j] = zf;

  for (int kt = 0; kt < K; kt += 32) {
    #pragma unroll
    for (int s = 0; s < 2; ++s) {
      int id = tid + (s << 8);           // 0..511
      int row = id >> 2, q = id & 3;
      size_t goA = (size_t)(m0 + row) * K + kt + (q << 3);
      int lo = swzA(row, q);
      *(short8v*)&sA[lo] = *(const short8v*)(Ah + goA);
      if constexpr (!BF32N) {
        size_t goB = (size_t)(n0 + row) * K + kt + (q << 3);
        *(short8v*)&sB[lo] = *(const short8v*)(Bh + goB);
        if constexpr (SPLIT) {
          *(short8v*)&sA2[lo] = *(const short8v*)(Al + goA);
          *(short8v*)&sB2[lo] = *(const short8v*)(Bl + goB);
        }
      }
    }
    if constexpr (BF32N) {
      // B[k][n] f32: k = tid>>3 in [0,32), 16 consecutive n per thread
      int k = tid >> 3, nc = (tid & 7) << 4;
      const float* bp = Bf + (size_t)(kt + k) * N + n0 + nc;
      int q = k >> 3, e = k & 7;
      #pragma unroll
      for (int j = 0; j < 16; ++j)
        sB[swzA(nc + j, q) + e] = f2bf(bp[j]);
    }
    __syncthreads();
    short8v af[4], bfr[4];
    #pragma unroll
    for (int i = 0; i < 4; ++i) {
      af[i]  = *(const short8v*)&sA[swzA((wr << 6) + (i << 4) + lm, lq)];
      bfr[i] = *(const short8v*)&sB[swzA((wc << 6) + (i << 4) + lm, lq)];
    }
    if constexpr (SPLIT) {
      short8v af2[4], bfr2[4];
      #pragma unroll
      for (int i = 0; i < 4; ++i) {
        af2[i]  = *(const short8v*)&sA2[swzA((wr << 6) + (i << 4) + lm, lq)];
        bfr2[i] = *(const short8v*)&sB2[swzA((wc << 6) + (i << 4) + lm, lq)];
      }
      #pragma unroll
      for (int mi = 0; mi < 4; ++mi)
        #pragma unroll
        for (int ni = 0; ni < 4; ++ni) {
          acc[mi][ni] = mfma16(af[mi],  bfr[ni],  acc[mi][ni]);
          acc[mi][ni] = mfma16(af2[mi], bfr[ni],  acc[mi][ni]);
          acc[mi][ni] = mfma16(af[mi],  bfr2[ni], acc[mi][ni]);
        }
    } else {
      #pragma unroll
      for (int mi = 0; mi < 4; ++mi)
        #pragma unroll
        for (int ni = 0; ni < 4; ++ni)
          acc[mi][ni] = mfma16(af[mi], bfr[ni], acc[mi][ni]);
    }
    __syncthreads();
  }
  #pragma unroll
  for (int mi = 0; mi < 4; ++mi)
    #pragma unroll
    for (int ni = 0; ni < 4; ++ni) {
      int col = n0 + (wc << 6) + (ni << 4) + lm;
      float bv = BIAS ? bias[col] : 0.f;
      #pragma unroll
      for (int i = 0; i < 4; ++i) {
        int row = m0 + (wr << 6) + (mi << 4) + (lq << 2) + i;
        float v = acc[mi][ni][i] + bv;
        size_t o = (size_t)row * N + col;
        if (OBF) Cb[o] = f2bf(v);
        else     C[o] = v;
      }
    }
}

// ---------------- persistent encoder: 32 blocks, 1 barrier/step ----------------
// block owns 16 h-columns; waves 0..2 hold Wh hi/lo fragments for gate g in registers.
// h kept as bf16 hi/lo pair (split-3 MFMA => ~fp16-accurate recurrence).
__global__ __launch_bounds__(256, 2) void k_encoder(
    const float* __restrict__ gx, const float* __restrict__ Wh,
    u16* hb, u16* __restrict__ ehs, unsigned* bc, unsigned* bf)
{
  __shared__ float rec_s[3][64][16];
  const int tid = threadIdx.x, bid = blockIdx.x;
  const int ln = tid & 63, wv = tid >> 6;
  const int lm = ln & 15, lq = ln >> 4, lq8 = lq << 3;

  short8v wfh[16], wfl[16];
  if (wv < 3) {
    const int col = (wv << 9) + (bid << 4) + lm;  // g*512 + j
    #pragma unroll
    for (int kt = 0; kt < 16; ++kt) {
      short8v a, b2;
      #pragma unroll
      for (int i = 0; i < 8; ++i) {
        float w = Wh[(size_t)((kt << 5) + lq8 + i) * G3_ + col];
        u16 hb2 = f2bf(w);
        a[i]  = (short)hb2;
        b2[i] = (short)f2bf(w - bf2f(hb2));
      }
      wfh[kt] = a; wfl[kt] = b2;
    }
  }
  { // zero h buffer 0 (hi+lo), own columns
    const int jx = tid & 15, bq = tid >> 4;
    const int jg = (bid << 4) + jx;
    #pragma unroll
    for (int i = 0; i < 4; ++i) {
      int b = (bq << 2) + i;
      hb[(b << 9) + jg] = 0;
      hb[32768 + (b << 9) + jg] = 0;
    }
  }
  unsigned dead = 0;
  unsigned gen = 1;
  gsync(bc, bf, 32u, gen, dead);
  const float4v zf = {0.f, 0.f, 0.f, 0.f};
  for (int t = 0; t < TS_; ++t) {
    const u16* hc = hb + ((t & 1) ? 65536 : 0);
    u16* hn = hb + ((t & 1) ? 0 : 65536);
    if (wv < 3) {
      float4v acc[4];
      #pragma unroll
      for (int mi = 0; mi < 4; ++mi) acc[mi] = zf;
      #pragma unroll
      for (int kt = 0; kt < 16; ++kt) {
        #pragma unroll
        for (int mi = 0; mi < 4; ++mi) {
          const u16* pa = hc + (((mi << 4) + lm) << 9) + (kt << 5) + lq8;
          short8v ah = *(const short8v*)pa;
          short8v al = *(const short8v*)(pa + 32768);
          acc[mi] = mfma16(ah, wfh[kt], acc[mi]);
          acc[mi] = mfma16(al, wfh[kt], acc[mi]);
          acc[mi] = mfma16(ah, wfl[kt], acc[mi]);
        }
      }
      #pragma unroll
      for (int mi = 0; mi < 4; ++mi)
        #pragma unroll
        for (int i = 0; i < 4; ++i)
          rec_s[wv][(mi << 4) + (lq << 2) + i][lm] = acc[mi][i];
    }
    __syncthreads();
    {
      const int jx = tid & 15, bq = tid >> 4;
      const int jg = (bid << 4) + jx;
      #pragma unroll
      for (int i = 0; i < 4; ++i) {
        int b = (bq << 2) + i;
        size_t rg = (size_t)((b << 8) + t) * G3_ + jg;
        float z   = sigm(gx[rg] + rec_s[0][b][jx]);
        float r   = sigm(gx[rg + 512] + rec_s[1][b][jx]);
        float hhv = tanhf(gx[rg + 1024] + r * rec_s[2][b][jx]);
        float hold = bf2f(hc[(b << 9) + jg]) + bf2f(hc[32768 + (b << 9) + jg]);
        float hnew = z * hold + (1.f - z) * hhv;
        u16 nh = f2bf(hnew);
        hn[(b << 9) + jg] = nh;
        hn[32768 + (b << 9) + jg] = f2bf(hnew - bf2f(nh));
        ehs[(size_t)((b << 8) + t) * 512 + jg] = nh;
      }
    }
    ++gen;
    gsync(bc, bf, 32u, gen, dead);
  }
}

// ---------------- persistent decoder: 32 rec + 128 attn = 160 blocks, 2 barriers/step ----------------
__global__ __launch_bounds__(256, 2) void k_decoder(
    const float* __restrict__ gxd, const float* __restrict__ Wh,
    const u16* __restrict__ att, const u16* __restrict__ e2,
    u16* hb, float* pnum, float* pden, u16* __restrict__ outs,
    unsigned* bc, unsigned* bf)
{
  __shared__ float rec_s[3][64][16];
  __shared__ float ps[128][2];
  __shared__ float es[128];
  __shared__ float wsum[2];
  const int tid = threadIdx.x, bid = blockIdx.x;
  const int ln = tid & 63, wv = tid >> 6;
  const int lm = ln & 15, lq = ln >> 4, lq8 = lq << 3;
  const bool isrec = (bid < 32);
  const int ab = bid - 32, batt = ab >> 1, cset = ab & 1;

  short8v wfh[16], wfl[16];
  if (isrec && wv < 3) {
    const int col = (wv << 9) + (bid << 4) + lm;
    #pragma unroll
    for (int kt = 0; kt < 16; ++kt) {
      short8v a, b2;
      #pragma unroll
      for (int i = 0; i < 8; ++i) {
        float w = Wh[(size_t)((kt << 5) + lq8 + i) * G3_ + col];
        u16 hb2 = f2bf(w);
        a[i]  = (short)hb2;
        b2[i] = (short)f2bf(w - bf2f(hb2));
      }
      wfh[kt] = a; wfl[kt] = b2;
    }
  }
  unsigned dead = 0;
  unsigned gen = 0;
  const float4v zf = {0.f, 0.f, 0.f, 0.f};
  for (int t = 0; t < TD_; ++t) {
    const u16* hc = hb + ((t & 1) ? 65536 : 0);
    u16* hn = hb + ((t & 1) ? 0 : 65536);
    if (isrec) {
      if (wv < 3) {
        float4v acc[4];
        #pragma unroll
        for (int mi = 0; mi < 4; ++mi) acc[mi] = zf;
        #pragma unroll
        for (int kt = 0; kt < 16; ++kt) {
          #pragma unroll
          for (int mi = 0; mi < 4; ++mi) {
            const u16* pa = hc + (((mi << 4) + lm) << 9) + (kt << 5) + lq8;
            short8v ah = *(const short8v*)pa;
            short8v al = *(const short8v*)(pa + 32768);
            acc[mi] = mfma16(ah, wfh[kt], acc[mi]);
            acc[mi] = mfma16(al, wfh[kt], acc[mi]);
            acc[mi] = mfma16(ah, wfl[kt], acc[mi]);
          }
        }
        #pragma unroll
        for (int mi = 0; mi < 4; ++mi)
          #pragma unroll
          for (int i = 0; i < 4; ++i)
            rec_s[wv][(mi << 4) + (lq << 2) + i][lm] = acc[mi][i];
      }
    } else {
      { // scores: 2-way k-split dot(E~[b, t'=cset*128+tt], h[b])
        int tt = tid >> 1, kq = tid & 1;
        const u16* ep = att + (size_t)((batt << 8) + (cset << 7) + tt) * 512 + (kq << 8);
        const u16* ph = hc + (batt << 9) + (kq << 8);
        const u16* pl = ph + 32768;
        float s = 0.f;
        #pragma unroll 4
        for (int k8 = 0; k8 < 32; ++k8) {
          short8v ev = *(const short8v*)(ep + (k8 << 3));
          short8v xh = *(const short8v*)(ph + (k8 << 3));
          short8v xl = *(const short8v*)(pl + (k8 << 3));
          #pragma unroll
          for (int i = 0; i < 8; ++i)
            s += bf2f((u16)ev[i]) * (bf2f((u16)xh[i]) + bf2f((u16)xl[i]));
        }
        ps[tt][kq] = s;
      }
      __syncthreads();
      if (tid < 128) {  // scores ~ +-0.3; exp without max is safe
        float e = expf(ps[tid][0] + ps[tid][1]);
        es[tid] = e;
        #pragma unroll
        for (int off = 32; off; off >>= 1) e += __shfl_down(e, off);
        if ((tid & 63) == 0) wsum[tid >> 6] = e;
      }
      __syncthreads();
      if (tid == 0) pden[(batt << 1) + cset] = wsum[0] + wsum[1];
      { // partial softmax-weighted sums over E~2 columns (6 cols/thread)
        int c0 = tid * 6;
        float a0=0.f,a1=0.f,a2=0.f,a3=0.f,a4=0.f,a5=0.f;
        const u16* base = e2 + (size_t)((batt << 8) + (cset << 7)) * G3_ + c0;
        for (int tt = 0; tt < 128; ++tt) {
          float ev = es[tt];
          const u16* p = base + (size_t)tt * G3_;
          a0 += ev * bf2f(p[0]); a1 += ev * bf2f(p[1]); a2 += ev * bf2f(p[2]);
          a3 += ev * bf2f(p[3]); a4 += ev * bf2f(p[4]); a5 += ev * bf2f(p[5]);
        }
        float* pn = pnum + (size_t)((batt << 1) + cset) * G3_ + c0;
        pn[0]=a0; pn[1]=a1; pn[2]=a2; pn[3]=a3; pn[4]=a4; pn[5]=a5;
      }
    }
    ++gen;
    gsync(bc, bf, 160u, gen, dead);
    if (isrec) { // gates
      const int jx = tid & 15, bq = tid >> 4;
      const int jg = (bid << 4) + jx;
      #pragma unroll
      for (int i = 0; i < 4; ++i) {
        int b = (bq << 2) + i;
        float den = pden[b << 1] + pden[(b << 1) + 1];
        float inv = 1.f / den;
        size_t rg = (size_t)((b << 6) + t) * G3_ + jg;
        float pz = 0.f, pr = 0.f, phh = 0.f;
        #pragma unroll
        for (int c = 0; c < 2; ++c) {
          const float* pp = pnum + (size_t)((b << 1) + c) * G3_;
          pz += pp[jg]; pr += pp[jg + 512]; phh += pp[jg + 1024];
        }
        float z   = sigm(gxd[rg] + pz * inv + rec_s[0][b][jx]);
        float r   = sigm(gxd[rg + 512] + pr * inv + rec_s[1][b][jx]);
        float hhv = tanhf(gxd[rg + 1024] + phh * inv + r * rec_s[2][b][jx]);
        float hold = bf2f(hc[(b << 9) + jg]) + bf2f(hc[32768 + (b << 9) + jg]);
        float hnew = z * hold + (1.f - z) * hhv;
        u16 nh = f2bf(hnew);
        hn[(b << 9) + jg] = nh;
        hn[32768 + (b << 9) + jg] = f2bf(hnew - bf2f(nh));
        outs[(size_t)((b << 6) + t) * 512 + jg] = nh;
      }
    }
    ++gen;
    gsync(bc, bf, 160u, gen, dead);
  }
}

extern "C" void kernel_launch(void* const* d_in, const int* in_sizes, int n_in,
                              void* d_out, int out_size, void* d_ws, size_t ws_size,
                              hipStream_t stream) {
  const int*   src_seq = (const int*)d_in[0];
  const int*   dec_seq = (const int*)d_in[1];
  const float* emb     = (const float*)d_in[2];
  const float* enc_Wx  = (const float*)d_in[3];
  const float* enc_Wh  = (const float*)d_in[4];
  const float* enc_b   = (const float*)d_in[5];
  const float* dec_Wx  = (const float*)d_in[6];
  const float* dec_Wh  = (const float*)d_in[7];
  const float* dec_b   = (const float*)d_in[8];
  const float* W_att   = (const float*)d_in[9];
  const float* Wd      = (const float*)d_in[10];
  const float* bd      = (const float*)d_in[11];

  // d_out (524,288,000 B) doubles as scratch; final projection reads ONLY ws+inputs
  // and overwrites all of d_out.
  char* ob = (char*)d_out;
  float* gx_all  = (float*)(ob + 0);           // [16384][1536] f32
  float* gxd_all = (float*)(ob + 100663296);   // [4096][1536] f32
  u16* srcE_h = (u16*)(ob + 125829120);        // [16384][512]
  u16* srcE_l = (u16*)(ob + 142606336);
  u16* decE_h = (u16*)(ob + 159383552);        // [4096][512]
  u16* decE_l = (u16*)(ob + 163577856);
  u16* ehs    = (u16*)(ob + 167772160);        // enc_hs bf16 [64][256][512]
  u16* attb   = (u16*)(ob + 184549376);        // E~ = ehs@W_att^T bf16
  u16* e2b    = (u16*)(ob + 201326592);        // E~2 = ehs@dec_Wx_ctx bf16 [16384][1536]
  u16* wxT_h  = (u16*)(ob + 251658240);        // enc_Wx^T [1536][512]
  u16* wxT_l  = (u16*)(ob + 253231104);
  u16* wdxT_h = (u16*)(ob + 254803968);        // dec_Wx[:512]^T
  u16* wdxT_l = (u16*)(ob + 256376832);
  u16* wxcT   = (u16*)(ob + 257949696);        // dec_Wx[512:]^T
  u16* watt   = (u16*)(ob + 259522560);        // W_att bf16 row-major
  u16* hbuf   = (u16*)(ob + 260046848);        // h dbl-buffer hi/lo, 262,144 B

  // workspace: 4,981,760 B needed
  char* wb = (char*)d_ws;
  u16* outs     = (u16*)(wb + 0);              // decoder outputs bf16 [4096][512]
  float* pnum   = (float*)(wb + 4194304);      // [128][1536]
  float* pden   = (float*)(wb + 4980736);      // [128]
  unsigned* bars = (unsigned*)(wb + 4981248);  // counters+flags
  (void)in_sizes; (void)n_in; (void)out_size; (void)ws_size;

  hipMemsetAsync(bars, 0, 512, stream);

  k_embed<<<4096, 256, 0, stream>>>(src_seq, emb, srcE_h, srcE_l, B_*TS_*64);
  k_embed<<<1024, 256, 0, stream>>>(dec_seq, emb, decE_h, decE_l, B_*TD_*64);
  k_transp<true ><<<dim3(24, 8), 256, 0, stream>>>(enc_Wx, G3_, wxT_h,  wxT_l,  512, G3_);
  k_transp<true ><<<dim3(24, 8), 256, 0, stream>>>(dec_Wx, G3_, wdxT_h, wdxT_l, 512, G3_);
  k_transp<false><<<dim3(24, 8), 256, 0, stream>>>(dec_Wx + (size_t)512*G3_, G3_, wxcT, nullptr, 512, G3_);
  k_cvt<<<1024, 256, 0, stream>>>(W_att, watt, 512*512);

  // gate-feeding input transforms: split-precision 3-term bf16 GEMMs
  k_gemm<true, false, true, false><<<dim3(12, 128), 256, 0, stream>>>(
      srcE_h, srcE_l, wxT_h, wxT_l, nullptr, gx_all, nullptr, enc_b, 16384, G3_, 512);
  k_gemm<true, false, true, false><<<dim3(12, 32), 256, 0, stream>>>(
      decE_h, decE_l, wdxT_h, wdxT_l, nullptr, gxd_all, nullptr, dec_b, 4096, G3_, 512);

  k_encoder<<<32, 256, 0, stream>>>(gx_all, enc_Wh, hbuf, ehs, bars + 0, bars + 32);

  // attention precomputes (bf16 is plenty on the attention path)
  k_gemm<false, false, false, true><<<dim3(4, 128), 256, 0, stream>>>(
      ehs, nullptr, watt, nullptr, nullptr, nullptr, attb, nullptr, 16384, 512, 512);
  k_gemm<false, false, false, true><<<dim3(12, 128), 256, 0, stream>>>(
      ehs, nullptr, wxcT, nullptr, nullptr, nullptr, e2b, nullptr, 16384, G3_, 512);

  k_decoder<<<160, 256, 0, stream>>>(gxd_all, dec_Wh, attb, e2b, hbuf, pnum, pden, outs,
                                     bars + 64, bars + 96);

  // vocab projection: A = outs (ws), B = Wd f32 [512][32000] on-the-fly, writes all of d_out
  k_gemm<false, true, true, false><<<dim3(250, 32), 256, 0, stream>>>(
      outs, nullptr, nullptr, nullptr, Wd, (float*)d_out, nullptr, bd, 4096, V_, 512);
}

// Round 3
// 9763.351 us; speedup vs baseline: 1.2925x; 1.2925x over previous
//
#include <hip/hip_runtime.h>
#include <stdint.h>
#include <math.h>

#define B_   64
#define TS_  256
#define TD_  64
#define H_   512
#define E_   512
#define V_   32000
#define G3_  1536

typedef unsigned short u16;
typedef __attribute__((ext_vector_type(8))) short  short8v;
typedef __attribute__((ext_vector_type(4))) float  float4v;

__device__ __forceinline__ u16 f2bf(float x) {
  union { float f; unsigned u; } v; v.f = x;
  unsigned r = v.u + 0x7FFFu + ((v.u >> 16) & 1u);
  return (u16)(r >> 16);
}
__device__ __forceinline__ float bf2f(u16 h) {
  union { unsigned u; float f; } v; v.u = ((unsigned)h) << 16; return v.f;
}
__device__ __forceinline__ float sigm(float x) { return 1.f / (1.f + expf(-x)); }

__device__ __forceinline__ float4v mfma16(short8v a, short8v b, float4v c) {
  return __builtin_amdgcn_mfma_f32_16x16x32_bf16(a, b, c, 0, 0, 0);
}

// ---- LLC-coherent (bypass L1/L2) access primitives ----
__device__ __forceinline__ void st2_sc(u16* p, u16 v) {
  unsigned vv = v;
  asm volatile("global_store_short %0, %1, off sc0 sc1" :: "v"(p), "v"(vv) : "memory");
}
__device__ __forceinline__ void st4_sc(float* p, float v) {
  asm volatile("global_store_dword %0, %1, off sc0 sc1" :: "v"(p), "v"(v) : "memory");
}
__device__ __forceinline__ void st8_sc(float* p, float2 v) {
  asm volatile("global_store_dwordx2 %0, %1, off sc0 sc1" :: "v"(p), "v"(v) : "memory");
}
__device__ __forceinline__ short8v ld16_sc(const u16* p) {
  short8v r;
  asm volatile("global_load_dwordx4 %0, %1, off sc0 sc1\ns_waitcnt vmcnt(0)"
               : "=v"(r) : "v"(p) : "memory");
  return r;
}
__device__ __forceinline__ unsigned ld_cnt(const unsigned* p) {
  unsigned r;
  asm volatile("global_load_dword %0, %1, off sc0 sc1\ns_waitcnt vmcnt(0)"
               : "=v"(r) : "v"(p) : "memory");
  return r;
}

// block-wide arrival: __syncthreads drains all threads' (sc1) stores, then one relaxed add
__device__ __forceinline__ void arrive_block(unsigned* cnt) {
  asm volatile("s_waitcnt vmcnt(0)" ::: "memory");
  __syncthreads();
  if (threadIdx.x == 0)
    __hip_atomic_fetch_add(cnt, 1u, __ATOMIC_RELAXED, __HIP_MEMORY_SCOPE_AGENT);
}

// wait until *cnt >= target; optional acquire fence (L1/L2 inv) for normal-load readers
__device__ __forceinline__ void sync_wait(unsigned* cnt, unsigned target,
                                          unsigned* sdead, bool fence) {
  __syncthreads();
  if (threadIdx.x == 0 && !*sdead) {
    unsigned spins = 0;
    while (ld_cnt(cnt) < target) {
      __builtin_amdgcn_s_sleep(1);
      if (++spins > (1u << 23)) { *sdead = 1u; break; }  // valve: never hang the harness
    }
  }
  __syncthreads();
  if (fence) __builtin_amdgcn_fence(__ATOMIC_ACQUIRE, "agent");
}

// ---------------- embedding gather + bf16 hi/lo split ----------------
__global__ __launch_bounds__(256) void k_embed(const int* __restrict__ seq,
    const float* __restrict__ emb, u16* __restrict__ hi, u16* __restrict__ lo, int total8) {
  int idx = blockIdx.x * 256 + threadIdx.x;
  if (idx >= total8) return;
  int row = idx >> 6;
  int c8  = (idx & 63) << 3;
  const float* src = emb + (size_t)seq[row] * E_ + c8;
  short8v hv, lv;
  #pragma unroll
  for (int i = 0; i < 8; ++i) {
    float x = src[i];
    u16 hb2 = f2bf(x);
    hv[i] = (short)hb2;
    lv[i] = (short)f2bf(x - bf2f(hb2));
  }
  *(short8v*)(hi + (size_t)idx * 8) = hv;
  *(short8v*)(lo + (size_t)idx * 8) = lv;
}

// ---------------- f32 [K][N] -> bf16 [N][K] transpose-convert (optional lo) ----------------
template<bool LO>
__global__ __launch_bounds__(256) void k_transp(const float* __restrict__ src, int ld,
    u16* __restrict__ dh, u16* __restrict__ dl, int K, int N) {
  __shared__ float t[64][65];
  int n0 = blockIdx.x << 6, k0 = blockIdx.y << 6;
  int c = threadIdx.x & 63, r0 = threadIdx.x >> 6;
  #pragma unroll
  for (int i = 0; i < 16; ++i) {
    int r = r0 + (i << 2);
    t[r][c] = src[(size_t)(k0 + r) * ld + n0 + c];
  }
  __syncthreads();
  #pragma unroll
  for (int i = 0; i < 16; ++i) {
    int rr = r0 + (i << 2);
    float v = t[c][rr];
    u16 hb2 = f2bf(v);
    size_t o = (size_t)(n0 + rr) * K + k0 + c;
    dh[o] = hb2;
    if (LO) dl[o] = f2bf(v - bf2f(hb2));
  }
}

__global__ __launch_bounds__(256) void k_cvt(const float* __restrict__ s, u16* __restrict__ d, int n) {
  int i = blockIdx.x * 256 + threadIdx.x;
  if (i < n) d[i] = f2bf(s[i]);
}

// ---------------- bf16 MFMA GEMM: C[M,N] = A[M,K] @ B^T (+bias) ----------------
__device__ __forceinline__ int swzA(int row, int q) {  // ushort offset within [128][32] tile
  return (row << 5) + ((q ^ ((row >> 1) & 3)) << 3);
}

template<bool SPLIT, bool BF32N, bool BIAS, bool OBF>
__global__ __launch_bounds__(256, 2) void k_gemm(
    const u16* __restrict__ Ah, const u16* __restrict__ Al,
    const u16* __restrict__ Bh, const u16* __restrict__ Bl,
    const float* __restrict__ Bf,
    float* __restrict__ C, u16* __restrict__ Cb, const float* __restrict__ bias,
    int M, int N, int K)
{
  __shared__ u16 sA[4096], sB[4096];
  __shared__ u16 sA2[SPLIT ? 4096 : 16], sB2[SPLIT ? 4096 : 16];
  const int tid = threadIdx.x;
  const int ln = tid & 63, wv = tid >> 6;
  const int wr = wv >> 1, wc = wv & 1;
  const int m0 = blockIdx.y << 7, n0 = blockIdx.x << 7;
  const int lm = ln & 15, lq = ln >> 4;
  const float4v zf = {0.f, 0.f, 0.f, 0.f};

  float4v acc[4][4];
  #pragma unroll
  for (int i = 0; i < 4; ++i)
    #pragma unroll
    for (int j = 0; j < 4; ++j) acc[i][j] = zf;

  for (int kt = 0; kt < K; kt += 32) {
    #pragma unroll
    for (int s = 0; s < 2; ++s) {
      int id = tid + (s << 8);           // 0..511
      int row = id >> 2, q = id & 3;
      size_t goA = (size_t)(m0 + row) * K + kt + (q << 3);
      int lo = swzA(row, q);
      *(short8v*)&sA[lo] = *(const short8v*)(Ah + goA);
      if constexpr (!BF32N) {
        size_t goB = (size_t)(n0 + row) * K + kt + (q << 3);
        *(short8v*)&sB[lo] = *(const short8v*)(Bh + goB);
        if constexpr (SPLIT) {
          *(short8v*)&sA2[lo] = *(const short8v*)(Al + goA);
          *(short8v*)&sB2[lo] = *(const short8v*)(Bl + goB);
        }
      }
    }
    if constexpr (BF32N) {
      int k = tid >> 3, nc = (tid & 7) << 4;
      const float* bp = Bf + (size_t)(kt + k) * N + n0 + nc;
      int q = k >> 3, e = k & 7;
      #pragma unroll
      for (int j = 0; j < 16; ++j)
        sB[swzA(nc + j, q) + e] = f2bf(bp[j]);
    }
    __syncthreads();
    short8v af[4], bfr[4];
    #pragma unroll
    for (int i = 0; i < 4; ++i) {
      af[i]  = *(const short8v*)&sA[swzA((wr << 6) + (i << 4) + lm, lq)];
      bfr[i] = *(const short8v*)&sB[swzA((wc << 6) + (i << 4) + lm, lq)];
    }
    if constexpr (SPLIT) {
      short8v af2[4], bfr2[4];
      #pragma unroll
      for (int i = 0; i < 4; ++i) {
        af2[i]  = *(const short8v*)&sA2[swzA((wr << 6) + (i << 4) + lm, lq)];
        bfr2[i] = *(const short8v*)&sB2[swzA((wc << 6) + (i << 4) + lm, lq)];
      }
      #pragma unroll
      for (int mi = 0; mi < 4; ++mi)
        #pragma unroll
        for (int ni = 0; ni < 4; ++ni) {
          acc[mi][ni] = mfma16(af[mi],  bfr[ni],  acc[mi][ni]);
          acc[mi][ni] = mfma16(af2[mi], bfr[ni],  acc[mi][ni]);
          acc[mi][ni] = mfma16(af[mi],  bfr2[ni], acc[mi][ni]);
        }
    } else {
      #pragma unroll
      for (int mi = 0; mi < 4; ++mi)
        #pragma unroll
        for (int ni = 0; ni < 4; ++ni)
          acc[mi][ni] = mfma16(af[mi], bfr[ni], acc[mi][ni]);
    }
    __syncthreads();
  }
  #pragma unroll
  for (int mi = 0; mi < 4; ++mi)
    #pragma unroll
    for (int ni = 0; ni < 4; ++ni) {
      int col = n0 + (wc << 6) + (ni << 4) + lm;
      float bv = BIAS ? bias[col] : 0.f;
      #pragma unroll
      for (int i = 0; i < 4; ++i) {
        int row = m0 + (wr << 6) + (mi << 4) + (lq << 2) + i;
        float v = acc[mi][ni][i] + bv;
        size_t o = (size_t)row * N + col;
        if (OBF) Cb[o] = f2bf(v);
        else     C[o] = v;
      }
    }
}

// ---------------- persistent encoder: 32 blocks, 1 counter-barrier/step ----------------
__global__ __launch_bounds__(256, 2) void k_encoder(
    const float* __restrict__ gx, const float* __restrict__ Wh,
    u16* hb, u16* __restrict__ ehs, unsigned* cnt)
{
  __shared__ float rec_s[3][64][16];
  __shared__ unsigned sdead;
  const int tid = threadIdx.x, bid = blockIdx.x;
  const int ln = tid & 63, wv = tid >> 6;
  const int lm = ln & 15, lq = ln >> 4, lq8 = lq << 3;
  if (tid == 0) sdead = 0;

  short8v wfh[16], wfl[16];
  if (wv < 3) {
    const int col = (wv << 9) + (bid << 4) + lm;  // g*512 + j
    #pragma unroll
    for (int kt = 0; kt < 16; ++kt) {
      short8v a, b2;
      #pragma unroll
      for (int i = 0; i < 8; ++i) {
        float w = Wh[(size_t)((kt << 5) + lq8 + i) * G3_ + col];
        u16 hb2 = f2bf(w);
        a[i]  = (short)hb2;
        b2[i] = (short)f2bf(w - bf2f(hb2));
      }
      wfh[kt] = a; wfl[kt] = b2;
    }
  }
  const int jx = tid & 15, bq = tid >> 4;
  const int jg = (bid << 4) + jx;
  #pragma unroll
  for (int i = 0; i < 4; ++i) {
    int b = (bq << 2) + i;
    st2_sc(hb + (b << 9) + jg, 0);
    st2_sc(hb + 32768 + (b << 9) + jg, 0);
  }
  arrive_block(cnt);
  unsigned done = 1;
  sync_wait(cnt, done * 32u, &sdead, true);

  const float4v zf = {0.f, 0.f, 0.f, 0.f};
  for (int t = 0; t < TS_; ++t) {
    const u16* hc = hb + ((t & 1) ? 65536 : 0);
    u16* hn = hb + ((t & 1) ? 0 : 65536);
    // prefetch gate inputs into registers (hidden under MFMA phase)
    float gz[4], gr[4], gh[4], hold[4];
    #pragma unroll
    for (int i = 0; i < 4; ++i) {
      int b = (bq << 2) + i;
      size_t rg = (size_t)((b << 8) + t) * G3_ + jg;
      gz[i] = gx[rg]; gr[i] = gx[rg + 512]; gh[i] = gx[rg + 1024];
      hold[i] = bf2f(hc[(b << 9) + jg]) + bf2f(hc[32768 + (b << 9) + jg]);
    }
    if (wv < 3) {
      float4v acc[4];
      #pragma unroll
      for (int mi = 0; mi < 4; ++mi) acc[mi] = zf;
      #pragma unroll
      for (int kt = 0; kt < 16; ++kt) {
        #pragma unroll
        for (int mi = 0; mi < 4; ++mi) {
          const u16* pa = hc + (((mi << 4) + lm) << 9) + (kt << 5) + lq8;
          short8v ah = *(const short8v*)pa;
          short8v al = *(const short8v*)(pa + 32768);
          acc[mi] = mfma16(ah, wfh[kt], acc[mi]);
          acc[mi] = mfma16(al, wfh[kt], acc[mi]);
          acc[mi] = mfma16(ah, wfl[kt], acc[mi]);
        }
      }
      #pragma unroll
      for (int mi = 0; mi < 4; ++mi)
        #pragma unroll
        for (int i = 0; i < 4; ++i)
          rec_s[wv][(mi << 4) + (lq << 2) + i][lm] = acc[mi][i];
    }
    __syncthreads();
    #pragma unroll
    for (int i = 0; i < 4; ++i) {
      int b = (bq << 2) + i;
      float z   = sigm(gz[i] + rec_s[0][b][jx]);
      float r   = sigm(gr[i] + rec_s[1][b][jx]);
      float hhv = tanhf(gh[i] + r * rec_s[2][b][jx]);
      float hnew = z * hold[i] + (1.f - z) * hhv;
      u16 nh = f2bf(hnew);
      st2_sc(hn + (b << 9) + jg, nh);
      st2_sc(hn + 32768 + (b << 9) + jg, f2bf(hnew - bf2f(nh)));
      ehs[(size_t)((b << 8) + t) * 512 + jg] = nh;
    }
    if (t < TS_ - 1) {
      arrive_block(cnt);
      ++done;
      sync_wait(cnt, done * 32u, &sdead, true);
    }
  }
}

// ---------------- persistent decoder: 32 rec + 128 attn, producer/consumer counters ----------------
__global__ __launch_bounds__(256, 2) void k_decoder(
    const float* __restrict__ gxd, const float* __restrict__ Wh,
    const u16* __restrict__ att, const u16* __restrict__ e2,
    u16* hb, float* pnum, float* pden, u16* __restrict__ outs,
    unsigned* hcnt, unsigned* pcnt)
{
  __shared__ float rec_s[3][64][16];
  __shared__ u16 shs[2][512];
  __shared__ float ps[128][2];
  __shared__ float es[128];
  __shared__ float wsum[2];
  __shared__ unsigned sdead;
  const int tid = threadIdx.x, bid = blockIdx.x;
  const int ln = tid & 63, wv = tid >> 6;
  const int lm = ln & 15, lq = ln >> 4, lq8 = lq << 3;
  const bool isrec = (bid < 32);
  const int ab = bid - 32, batt = ab >> 1, cset = ab & 1;
  if (tid == 0) sdead = 0;
  __syncthreads();

  short8v wfh[16], wfl[16];
  if (isrec && wv < 3) {
    const int col = (wv << 9) + (bid << 4) + lm;
    #pragma unroll
    for (int kt = 0; kt < 16; ++kt) {
      short8v a, b2;
      #pragma unroll
      for (int i = 0; i < 8; ++i) {
        float w = Wh[(size_t)((kt << 5) + lq8 + i) * G3_ + col];
        u16 hb2 = f2bf(w);
        a[i]  = (short)hb2;
        b2[i] = (short)f2bf(w - bf2f(hb2));
      }
      wfh[kt] = a; wfl[kt] = b2;
    }
  }
  const float4v zf = {0.f, 0.f, 0.f, 0.f};
  for (int t = 0; t < TD_; ++t) {
    const u16* hc = hb + ((t & 1) ? 65536 : 0);
    u16* hn = hb + ((t & 1) ? 0 : 65536);
    if (isrec) {
      if (t) sync_wait(hcnt, 32u * (unsigned)t, &sdead, true);
      const int jx = tid & 15, bq = tid >> 4;
      const int jg = (bid << 4) + jx;
      float gz[4], gr[4], gh[4], hold[4];
      #pragma unroll
      for (int i = 0; i < 4; ++i) {
        int b = (bq << 2) + i;
        size_t rg = (size_t)((b << 6) + t) * G3_ + jg;
        gz[i] = gxd[rg]; gr[i] = gxd[rg + 512]; gh[i] = gxd[rg + 1024];
        hold[i] = bf2f(hc[(b << 9) + jg]) + bf2f(hc[32768 + (b << 9) + jg]);
      }
      if (wv < 3) {
        float4v acc[4];
        #pragma unroll
        for (int mi = 0; mi < 4; ++mi) acc[mi] = zf;
        #pragma unroll
        for (int kt = 0; kt < 16; ++kt) {
          #pragma unroll
          for (int mi = 0; mi < 4; ++mi) {
            const u16* pa = hc + (((mi << 4) + lm) << 9) + (kt << 5) + lq8;
            short8v ah = *(const short8v*)pa;
            short8v al = *(const short8v*)(pa + 32768);
            acc[mi] = mfma16(ah, wfh[kt], acc[mi]);
            acc[mi] = mfma16(al, wfh[kt], acc[mi]);
            acc[mi] = mfma16(ah, wfl[kt], acc[mi]);
          }
        }
        #pragma unroll
        for (int mi = 0; mi < 4; ++mi)
          #pragma unroll
          for (int i = 0; i < 4; ++i)
            rec_s[wv][(mi << 4) + (lq << 2) + i][lm] = acc[mi][i];
      }
      __syncthreads();
      sync_wait(pcnt, 128u * (unsigned)(t + 1), &sdead, true);
      #pragma unroll
      for (int i = 0; i < 4; ++i) {
        int b = (bq << 2) + i;
        float den = pden[b << 1] + pden[(b << 1) + 1];
        float inv = 1.f / den;
        float pz = 0.f, pr = 0.f, phh = 0.f;
        #pragma unroll
        for (int c = 0; c < 2; ++c) {
          const float* pp = pnum + (size_t)((b << 1) + c) * G3_;
          pz += pp[jg]; pr += pp[jg + 512]; phh += pp[jg + 1024];
        }
        float z   = sigm(gz[i] + pz * inv + rec_s[0][b][jx]);
        float r   = sigm(gr[i] + pr * inv + rec_s[1][b][jx]);
        float hhv = tanhf(gh[i] + phh * inv + r * rec_s[2][b][jx]);
        float hnew = z * hold[i] + (1.f - z) * hhv;
        u16 nh = f2bf(hnew);
        st2_sc(hn + (b << 9) + jg, nh);
        st2_sc(hn + 32768 + (b << 9) + jg, f2bf(hnew - bf2f(nh)));
        outs[(size_t)((b << 6) + t) * 512 + jg] = nh;
      }
      arrive_block(hcnt);
    } else {
      if (t) sync_wait(hcnt, 32u * (unsigned)t, &sdead, false);
      // stage h (hi+lo) for this batch into LDS via LLC-coherent loads
      if (tid < 128) {
        int half = tid >> 6, c = tid & 63;
        short8v hv = ld16_sc(hc + (batt << 9) + (half ? 32768 : 0) + (c << 3));
        *(short8v*)&shs[half][c << 3] = hv;
      }
      __syncthreads();
      { // scores: 2-way k-split dot(E~[b, t'=cset*128+tt], h[b])
        int tt = tid >> 1, kq = tid & 1;
        const u16* ep = att + (size_t)((batt << 8) + (cset << 7) + tt) * 512 + (kq << 8);
        float s = 0.f;
        #pragma unroll 4
        for (int k8 = 0; k8 < 32; ++k8) {
          short8v ev = *(const short8v*)(ep + (k8 << 3));
          short8v xh = *(const short8v*)&shs[0][(kq << 8) + (k8 << 3)];
          short8v xl = *(const short8v*)&shs[1][(kq << 8) + (k8 << 3)];
          #pragma unroll
          for (int i = 0; i < 8; ++i)
            s += bf2f((u16)ev[i]) * (bf2f((u16)xh[i]) + bf2f((u16)xl[i]));
        }
        ps[tt][kq] = s;
      }
      __syncthreads();
      if (tid < 128) {  // scores are small; exp without max is safe
        float e = expf(ps[tid][0] + ps[tid][1]);
        es[tid] = e;
        #pragma unroll
        for (int off = 32; off; off >>= 1) e += __shfl_down(e, off);
        if ((tid & 63) == 0) wsum[tid >> 6] = e;
      }
      __syncthreads();
      if (tid == 0) st4_sc(&pden[(batt << 1) + cset], wsum[0] + wsum[1]);
      { // partial softmax-weighted sums over E~2 columns (6 cols/thread)
        int c0 = tid * 6;
        float a0=0.f,a1=0.f,a2=0.f,a3=0.f,a4=0.f,a5=0.f;
        const u16* base = e2 + (size_t)((batt << 8) + (cset << 7)) * G3_ + c0;
        for (int tt = 0; tt < 128; ++tt) {
          float ev = es[tt];
          const u16* p = base + (size_t)tt * G3_;
          a0 += ev * bf2f(p[0]); a1 += ev * bf2f(p[1]); a2 += ev * bf2f(p[2]);
          a3 += ev * bf2f(p[3]); a4 += ev * bf2f(p[4]); a5 += ev * bf2f(p[5]);
        }
        float* pn = pnum + (size_t)((batt << 1) + cset) * G3_ + c0;
        float2 v01 = {a0, a1}, v23 = {a2, a3}, v45 = {a4, a5};
        st8_sc(pn, v01); st8_sc(pn + 2, v23); st8_sc(pn + 4, v45);
      }
      arrive_block(pcnt);
    }
  }
}

extern "C" void kernel_launch(void* const* d_in, const int* in_sizes, int n_in,
                              void* d_out, int out_size, void* d_ws, size_t ws_size,
                              hipStream_t stream) {
  const int*   src_seq = (const int*)d_in[0];
  const int*   dec_seq = (const int*)d_in[1];
  const float* emb     = (const float*)d_in[2];
  const float* enc_Wx  = (const float*)d_in[3];
  const float* enc_Wh  = (const float*)d_in[4];
  const float* enc_b   = (const float*)d_in[5];
  const float* dec_Wx  = (const float*)d_in[6];
  const float* dec_Wh  = (const float*)d_in[7];
  const float* dec_b   = (const float*)d_in[8];
  const float* W_att   = (const float*)d_in[9];
  const float* Wd      = (const float*)d_in[10];
  const float* bd      = (const float*)d_in[11];

  // d_out (524,288,000 B) doubles as scratch; final projection reads ONLY ws+inputs.
  char* ob = (char*)d_out;
  float* gx_all  = (float*)(ob + 0);           // [16384][1536] f32
  float* gxd_all = (float*)(ob + 100663296);   // [4096][1536] f32
  u16* srcE_h = (u16*)(ob + 125829120);        // [16384][512]
  u16* srcE_l = (u16*)(ob + 142606336);
  u16* decE_h = (u16*)(ob + 159383552);        // [4096][512]
  u16* decE_l = (u16*)(ob + 163577856);
  u16* ehs    = (u16*)(ob + 167772160);        // enc_hs bf16 [64][256][512]
  u16* attb   = (u16*)(ob + 184549376);        // E~ = ehs@W_att^T bf16
  u16* e2b    = (u16*)(ob + 201326592);        // E~2 = ehs@dec_Wx_ctx bf16 [16384][1536]
  u16* wxT_h  = (u16*)(ob + 251658240);        // enc_Wx^T [1536][512]
  u16* wxT_l  = (u16*)(ob + 253231104);
  u16* wdxT_h = (u16*)(ob + 254803968);        // dec_Wx[:512]^T
  u16* wdxT_l = (u16*)(ob + 256376832);
  u16* wxcT   = (u16*)(ob + 257949696);        // dec_Wx[512:]^T
  u16* watt   = (u16*)(ob + 259522560);        // W_att bf16 row-major
  u16* hbuf   = (u16*)(ob + 260046848);        // h dbl-buffer hi/lo, 262,144 B

  char* wb = (char*)d_ws;
  u16* outs     = (u16*)(wb + 0);              // decoder outputs bf16 [4096][512]
  float* pnum   = (float*)(wb + 4194304);      // [128][1536]
  float* pden   = (float*)(wb + 4980736);      // [128]
  unsigned* bars = (unsigned*)(wb + 4981248);  // counters
  (void)in_sizes; (void)n_in; (void)out_size; (void)ws_size;

  hipMemsetAsync(bars, 0, 256, stream);

  k_embed<<<4096, 256, 0, stream>>>(src_seq, emb, srcE_h, srcE_l, B_*TS_*64);
  k_embed<<<1024, 256, 0, stream>>>(dec_seq, emb, decE_h, decE_l, B_*TD_*64);
  k_transp<true ><<<dim3(24, 8), 256, 0, stream>>>(enc_Wx, G3_, wxT_h,  wxT_l,  512, G3_);
  k_transp<true ><<<dim3(24, 8), 256, 0, stream>>>(dec_Wx, G3_, wdxT_h, wdxT_l, 512, G3_);
  k_transp<false><<<dim3(24, 8), 256, 0, stream>>>(dec_Wx + (size_t)512*G3_, G3_, wxcT, nullptr, 512, G3_);
  k_cvt<<<1024, 256, 0, stream>>>(W_att, watt, 512*512);

  // gate-feeding input transforms: split-precision 3-term bf16 GEMMs
  k_gemm<true, false, true, false><<<dim3(12, 128), 256, 0, stream>>>(
      srcE_h, srcE_l, wxT_h, wxT_l, nullptr, gx_all, nullptr, enc_b, 16384, G3_, 512);
  k_gemm<true, false, true, false><<<dim3(12, 32), 256, 0, stream>>>(
      decE_h, decE_l, wdxT_h, wdxT_l, nullptr, gxd_all, nullptr, dec_b, 4096, G3_, 512);

  k_encoder<<<32, 256, 0, stream>>>(gx_all, enc_Wh, hbuf, ehs, bars + 0);

  // attention precomputes (bf16 is plenty on the attention path)
  k_gemm<false, false, false, true><<<dim3(4, 128), 256, 0, stream>>>(
      ehs, nullptr, watt, nullptr, nullptr, nullptr, attb, nullptr, 16384, 512, 512);
  k_gemm<false, false, false, true><<<dim3(12, 128), 256, 0, stream>>>(
      ehs, nullptr, wxcT, nullptr, nullptr, nullptr, e2b, nullptr, 16384, G3_, 512);

  k_decoder<<<160, 256, 0, stream>>>(gxd_all, dec_Wh, attb, e2b, hbuf, pnum, pden, outs,
                                     bars + 16, bars + 32);

  // vocab projection: A = outs (ws), B = Wd f32 [512][32000] on-the-fly, writes all of d_out
  k_gemm<false, true, true, false><<<dim3(250, 32), 256, 0, stream>>>(
      outs, nullptr, nullptr, nullptr, Wd, (float*)d_out, nullptr, bd, 4096, V_, 512);
}

// Round 4
// 3128.365 us; speedup vs baseline: 4.0338x; 3.1209x over previous
//
#include <hip/hip_runtime.h>
#include <stdint.h>
#include <math.h>

#define B_   64
#define TS_  256
#define TD_  64
#define H_   512
#define E_   512
#define V_   32000
#define G3_  1536

// barrier dword offsets in bars[]
#define ENC_G 0
#define ENC_T 128
#define ENC_F 160
#define DH_G  192
#define DH_T  320
#define DH_F  352
#define DP_G  384
#define DP_T  512
#define DP_F  544

typedef unsigned short u16;
typedef __attribute__((ext_vector_type(8))) short  short8v;
typedef __attribute__((ext_vector_type(4))) float  float4v;

__device__ __forceinline__ u16 f2bf(float x) {
  union { float f; unsigned u; } v; v.f = x;
  unsigned r = v.u + 0x7FFFu + ((v.u >> 16) & 1u);
  return (u16)(r >> 16);
}
__device__ __forceinline__ float bf2f(u16 h) {
  union { unsigned u; float f; } v; v.u = ((unsigned)h) << 16; return v.f;
}
__device__ __forceinline__ float sigm(float x) { return 1.f / (1.f + expf(-x)); }

__device__ __forceinline__ float4v mfma16(short8v a, short8v b, float4v c) {
  return __builtin_amdgcn_mfma_f32_16x16x32_bf16(a, b, c, 0, 0, 0);
}

// ---- LLC-coherent primitives (bypass L1/L2; no fences needed anywhere) ----
__device__ __forceinline__ void st2_sc(u16* p, u16 v) {
  unsigned vv = v;
  asm volatile("global_store_short %0, %1, off sc0 sc1" :: "v"(p), "v"(vv) : "memory");
}
__device__ __forceinline__ void st4_sc(float* p, float v) {
  asm volatile("global_store_dword %0, %1, off sc0 sc1" :: "v"(p), "v"(v) : "memory");
}
__device__ __forceinline__ void st4u_sc(unsigned* p, unsigned v) {
  asm volatile("global_store_dword %0, %1, off sc0 sc1" :: "v"(p), "v"(v) : "memory");
}
__device__ __forceinline__ void st8_sc(float* p, float2 v) {
  asm volatile("global_store_dwordx2 %0, %1, off sc0 sc1" :: "v"(p), "v"(v) : "memory");
}
__device__ __forceinline__ short8v ld16_sc(const u16* p) {
  short8v r;
  asm volatile("global_load_dwordx4 %0, %1, off sc0 sc1\ns_waitcnt vmcnt(0)"
               : "=v"(r) : "v"(p) : "memory");
  return r;
}
__device__ __forceinline__ unsigned ld_cnt(const unsigned* p) {
  unsigned r;
  asm volatile("global_load_dword %0, %1, off sc0 sc1\ns_waitcnt vmcnt(0)"
               : "=v"(r) : "v"(p) : "memory");
  return r;
}

// hierarchical arrival: group counter (32 blocks) -> top counter -> epoch flag
__device__ __forceinline__ void block_arrive(unsigned* bars, int goff, int grp,
                                             int toff, int foff, unsigned ngrp, unsigned step) {
  asm volatile("s_waitcnt vmcnt(0)" ::: "memory");
  __syncthreads();
  if (threadIdx.x == 0) {
    unsigned o = __hip_atomic_fetch_add(bars + goff + (grp << 5), 1u,
                                        __ATOMIC_RELAXED, __HIP_MEMORY_SCOPE_AGENT);
    if (o == step * 32u - 1u) {
      unsigned o2 = __hip_atomic_fetch_add(bars + toff, 1u,
                                           __ATOMIC_RELAXED, __HIP_MEMORY_SCOPE_AGENT);
      if (o2 == step * ngrp - 1u)
        st4u_sc(bars + foff, step);
    }
  }
}
// spin on epoch flag (plain sc loads, own cache line, no RMW contention)
__device__ __forceinline__ void wait_flag(unsigned* bars, int foff, unsigned step, unsigned* sdead) {
  __syncthreads();
  if (threadIdx.x == 0 && !*sdead) {
    unsigned spins = 0;
    while (ld_cnt(bars + foff) < step) {
      __builtin_amdgcn_s_sleep(4);
      if (++spins > (1u << 23)) { *sdead = 1u; break; }  // valve: never hang harness
    }
  }
  __syncthreads();
}

// ---------------- embedding gather + bf16 hi/lo split ----------------
__global__ __launch_bounds__(256) void k_embed(const int* __restrict__ seq,
    const float* __restrict__ emb, u16* __restrict__ hi, u16* __restrict__ lo, int total8) {
  int idx = blockIdx.x * 256 + threadIdx.x;
  if (idx >= total8) return;
  int row = idx >> 6;
  int c8  = (idx & 63) << 3;
  const float* src = emb + (size_t)seq[row] * E_ + c8;
  short8v hv, lv;
  #pragma unroll
  for (int i = 0; i < 8; ++i) {
    float x = src[i];
    u16 hb2 = f2bf(x);
    hv[i] = (short)hb2;
    lv[i] = (short)f2bf(x - bf2f(hb2));
  }
  *(short8v*)(hi + (size_t)idx * 8) = hv;
  *(short8v*)(lo + (size_t)idx * 8) = lv;
}

// ---------------- f32 [K][N] -> bf16 [N][K] transpose-convert (optional lo) ----------------
template<bool LO>
__global__ __launch_bounds__(256) void k_transp(const float* __restrict__ src, int ld,
    u16* __restrict__ dh, u16* __restrict__ dl, int K, int N) {
  __shared__ float t[64][65];
  int n0 = blockIdx.x << 6, k0 = blockIdx.y << 6;
  int c = threadIdx.x & 63, r0 = threadIdx.x >> 6;
  #pragma unroll
  for (int i = 0; i < 16; ++i) {
    int r = r0 + (i << 2);
    t[r][c] = src[(size_t)(k0 + r) * ld + n0 + c];
  }
  __syncthreads();
  #pragma unroll
  for (int i = 0; i < 16; ++i) {
    int rr = r0 + (i << 2);
    float v = t[c][rr];
    u16 hb2 = f2bf(v);
    size_t o = (size_t)(n0 + rr) * K + k0 + c;
    dh[o] = hb2;
    if (LO) dl[o] = f2bf(v - bf2f(hb2));
  }
}

__global__ __launch_bounds__(256) void k_cvt(const float* __restrict__ s, u16* __restrict__ d, int n) {
  int i = blockIdx.x * 256 + threadIdx.x;
  if (i < n) d[i] = f2bf(s[i]);
}

// ---------------- bf16 MFMA GEMM: C[M,N] = A[M,K] @ B^T (+bias) ----------------
__device__ __forceinline__ int swzA(int row, int q) {  // ushort offset within [128][32] tile
  return (row << 5) + ((q ^ ((row >> 1) & 3)) << 3);
}

template<bool SPLIT, bool BF32N, bool BIAS, bool OBF>
__global__ __launch_bounds__(256, 2) void k_gemm(
    const u16* __restrict__ Ah, const u16* __restrict__ Al,
    const u16* __restrict__ Bh, const u16* __restrict__ Bl,
    const float* __restrict__ Bf,
    float* __restrict__ C, u16* __restrict__ Cb, const float* __restrict__ bias,
    int M, int N, int K)
{
  __shared__ u16 sA[4096], sB[4096];
  __shared__ u16 sA2[SPLIT ? 4096 : 16], sB2[SPLIT ? 4096 : 16];
  const int tid = threadIdx.x;
  const int ln = tid & 63, wv = tid >> 6;
  const int wr = wv >> 1, wc = wv & 1;
  const int m0 = blockIdx.y << 7, n0 = blockIdx.x << 7;
  const int lm = ln & 15, lq = ln >> 4;
  const float4v zf = {0.f, 0.f, 0.f, 0.f};

  float4v acc[4][4];
  #pragma unroll
  for (int i = 0; i < 4; ++i)
    #pragma unroll
    for (int j = 0; j < 4; ++j) acc[i][j] = zf;

  for (int kt = 0; kt < K; kt += 32) {
    #pragma unroll
    for (int s = 0; s < 2; ++s) {
      int id = tid + (s << 8);           // 0..511
      int row = id >> 2, q = id & 3;
      size_t goA = (size_t)(m0 + row) * K + kt + (q << 3);
      int lo = swzA(row, q);
      *(short8v*)&sA[lo] = *(const short8v*)(Ah + goA);
      if constexpr (!BF32N) {
        size_t goB = (size_t)(n0 + row) * K + kt + (q << 3);
        *(short8v*)&sB[lo] = *(const short8v*)(Bh + goB);
        if constexpr (SPLIT) {
          *(short8v*)&sA2[lo] = *(const short8v*)(Al + goA);
          *(short8v*)&sB2[lo] = *(const short8v*)(Bl + goB);
        }
      }
    }
    if constexpr (BF32N) {
      int k = tid >> 3, nc = (tid & 7) << 4;
      const float* bp = Bf + (size_t)(kt + k) * N + n0 + nc;
      int q = k >> 3, e = k & 7;
      #pragma unroll
      for (int j = 0; j < 16; ++j)
        sB[swzA(nc + j, q) + e] = f2bf(bp[j]);
    }
    __syncthreads();
    short8v af[4], bfr[4];
    #pragma unroll
    for (int i = 0; i < 4; ++i) {
      af[i]  = *(const short8v*)&sA[swzA((wr << 6) + (i << 4) + lm, lq)];
      bfr[i] = *(const short8v*)&sB[swzA((wc << 6) + (i << 4) + lm, lq)];
    }
    if constexpr (SPLIT) {
      short8v af2[4], bfr2[4];
      #pragma unroll
      for (int i = 0; i < 4; ++i) {
        af2[i]  = *(const short8v*)&sA2[swzA((wr << 6) + (i << 4) + lm, lq)];
        bfr2[i] = *(const short8v*)&sB2[swzA((wc << 6) + (i << 4) + lm, lq)];
      }
      #pragma unroll
      for (int mi = 0; mi < 4; ++mi)
        #pragma unroll
        for (int ni = 0; ni < 4; ++ni) {
          acc[mi][ni] = mfma16(af[mi],  bfr[ni],  acc[mi][ni]);
          acc[mi][ni] = mfma16(af2[mi], bfr[ni],  acc[mi][ni]);
          acc[mi][ni] = mfma16(af[mi],  bfr2[ni], acc[mi][ni]);
        }
    } else {
      #pragma unroll
      for (int mi = 0; mi < 4; ++mi)
        #pragma unroll
        for (int ni = 0; ni < 4; ++ni)
          acc[mi][ni] = mfma16(af[mi], bfr[ni], acc[mi][ni]);
    }
    __syncthreads();
  }
  #pragma unroll
  for (int mi = 0; mi < 4; ++mi)
    #pragma unroll
    for (int ni = 0; ni < 4; ++ni) {
      int col = n0 + (wc << 6) + (ni << 4) + lm;
      float bv = BIAS ? bias[col] : 0.f;
      #pragma unroll
      for (int i = 0; i < 4; ++i) {
        int row = m0 + (wr << 6) + (mi << 4) + (lq << 2) + i;
        float v = acc[mi][ni][i] + bv;
        size_t o = (size_t)row * N + col;
        if (OBF) Cb[o] = f2bf(v);
        else     C[o] = v;
      }
    }
}

// ---------------- persistent encoder: 128 blocks (4 batch-sets x 32 col-blocks) ----------------
// per step: sc-load h slice (32KB) -> LDS (XOR-swizzled), MFMA r = h@Wh (regs), gates, sc-store h.
__global__ __launch_bounds__(256, 1) void k_encoder(
    const float* __restrict__ gx, const float* __restrict__ Wh,
    u16* hb, u16* __restrict__ ehs, unsigned* bars)
{
  __shared__ char smem[32768];          // [2(hi/lo)][16 rows][512 cols] bf16, swizzled
  __shared__ float rec_s[3][16][16];
  __shared__ unsigned sdead;
  const int tid = threadIdx.x, bid = blockIdx.x;
  const int ln = tid & 63, wv = tid >> 6;
  const int lm = ln & 15, lq = ln >> 4, lq8 = lq << 3;
  const int set = bid >> 5, colblk = bid & 31, grp = bid >> 5;
  const int s16 = set << 4;
  const int jx = tid & 15, bl = tid >> 4;
  const int jg = (colblk << 4) + jx;
  const int b  = s16 + bl;
  if (tid == 0) sdead = 0;

  short8v wfh[16], wfl[16];
  if (wv < 3) {
    const int col = (wv << 9) + (colblk << 4) + lm;  // gate*512 + j
    #pragma unroll
    for (int kt = 0; kt < 16; ++kt) {
      short8v a, b2;
      #pragma unroll
      for (int i = 0; i < 8; ++i) {
        float w = Wh[(size_t)((kt << 5) + lq8 + i) * G3_ + col];
        u16 hb2 = f2bf(w);
        a[i]  = (short)hb2;
        b2[i] = (short)f2bf(w - bf2f(hb2));
      }
      wfh[kt] = a; wfl[kt] = b2;
    }
  }
  const float4v zf = {0.f, 0.f, 0.f, 0.f};
  for (int t = 0; t < TS_; ++t) {
    if (t == 0) {  // h(0)=0: zero LDS, no global traffic, no barrier
      short8v zz = {0,0,0,0,0,0,0,0};
      #pragma unroll
      for (int i = 0; i < 8; ++i)
        *(short8v*)(smem + ((tid + (i << 8)) << 4)) = zz;
      __syncthreads();
    } else {
      wait_flag(bars, ENC_F, (unsigned)t, &sdead);
      const u16* cur = hb + ((t & 1) ? 65536 : 0);
      short8v v[8];
      #pragma unroll
      for (int i = 0; i < 8; ++i) {
        int c = tid + (i << 8);
        int half = c >> 10, rem = c & 1023;
        int r = rem >> 6, col16 = rem & 63;
        const u16* p = cur + (half << 15) + ((s16 + r) << 9) + (col16 << 3);
        asm volatile("global_load_dwordx4 %0, %1, off sc0 sc1" : "=v"(v[i]) : "v"(p));
      }
      asm volatile("s_waitcnt vmcnt(0)" ::: "memory");
      __builtin_amdgcn_sched_barrier(0);
      #pragma unroll
      for (int i = 0; i < 8; ++i) {
        int c = tid + (i << 8);
        int half = c >> 10, rem = c & 1023;
        int r = rem >> 6, col16 = rem & 63;
        *(short8v*)(smem + ((half << 14) | (r << 10) | ((col16 << 4) ^ ((r & 7) << 4)))) = v[i];
      }
      __syncthreads();
    }
    // gate inputs + hold (LDS)
    float gzv, grv, ghv;
    {
      size_t rg = (size_t)((b << 8) + t) * G3_ + jg;
      gzv = gx[rg]; grv = gx[rg + 512]; ghv = gx[rg + 1024];
    }
    int hoff = (bl << 10) | ((jg << 1) ^ ((bl & 7) << 4));
    float hold = bf2f(*(const u16*)(smem + hoff)) + bf2f(*(const u16*)(smem + 16384 + hoff));
    if (wv < 3) {
      float4v acc = zf;
      #pragma unroll
      for (int kt = 0; kt < 16; ++kt) {
        int aoff = (lm << 10) | (((kt << 6) + (lq << 4)) ^ ((lm & 7) << 4));
        short8v ah = *(const short8v*)(smem + aoff);
        short8v al = *(const short8v*)(smem + 16384 + aoff);
        acc = mfma16(ah, wfh[kt], acc);
        acc = mfma16(al, wfh[kt], acc);
        acc = mfma16(ah, wfl[kt], acc);
      }
      #pragma unroll
      for (int i = 0; i < 4; ++i) rec_s[wv][(lq << 2) + i][lm] = acc[i];
    }
    __syncthreads();
    {
      float z  = sigm(gzv + rec_s[0][bl][jx]);
      float r  = sigm(grv + rec_s[1][bl][jx]);
      float hh = tanhf(ghv + r * rec_s[2][bl][jx]);
      float hnew = z * hold + (1.f - z) * hh;
      u16 nh = f2bf(hnew);
      u16* hnx = hb + ((t & 1) ? 0 : 65536);
      st2_sc(hnx + (b << 9) + jg, nh);
      st2_sc(hnx + 32768 + (b << 9) + jg, f2bf(hnew - bf2f(nh)));
      ehs[(size_t)((b << 8) + t) * 512 + jg] = nh;
    }
    if (t < TS_ - 1)
      block_arrive(bars, ENC_G, grp, ENC_T, ENC_F, 4u, (unsigned)(t + 1));
  }
}

// ---------------- persistent decoder: 128 rec (4 sets x 32) + 128 attn ----------------
__global__ __launch_bounds__(256, 1) void k_decoder(
    const float* __restrict__ gxd, const float* __restrict__ Wh,
    const u16* __restrict__ att, const u16* __restrict__ e2,
    u16* hb, float* pnum, float* pden, u16* __restrict__ outs, unsigned* bars)
{
  __shared__ char smem[32768];
  __shared__ float rec_s[3][16][16];
  __shared__ u16 shs[2][512];
  __shared__ float ps[128][2];
  __shared__ float es[128];
  __shared__ float wsum[2];
  __shared__ unsigned sdead;
  const int tid = threadIdx.x, bid = blockIdx.x;
  const int ln = tid & 63, wv = tid >> 6;
  const int lm = ln & 15, lq = ln >> 4, lq8 = lq << 3;
  const bool isrec = (bid < 128);
  const int set = bid >> 5, colblk = bid & 31;
  const int s16 = set << 4;
  const int jx = tid & 15, bl = tid >> 4;
  const int jg = (colblk << 4) + jx;
  const int b  = s16 + bl;
  const int ab = bid - 128, batt = ab >> 1, cset = ab & 1;
  if (tid == 0) sdead = 0;
  __syncthreads();

  short8v wfh[16], wfl[16];
  if (isrec && wv < 3) {
    const int col = (wv << 9) + (colblk << 4) + lm;
    #pragma unroll
    for (int kt = 0; kt < 16; ++kt) {
      short8v a, b2;
      #pragma unroll
      for (int i = 0; i < 8; ++i) {
        float w = Wh[(size_t)((kt << 5) + lq8 + i) * G3_ + col];
        u16 hb2 = f2bf(w);
        a[i]  = (short)hb2;
        b2[i] = (short)f2bf(w - bf2f(hb2));
      }
      wfh[kt] = a; wfl[kt] = b2;
    }
  }
  const float4v zf = {0.f, 0.f, 0.f, 0.f};
  for (int t = 0; t < TD_; ++t) {
    const u16* cur = hb + ((t & 1) ? 65536 : 0);
    if (isrec) {
      if (t) wait_flag(bars, DH_F, (unsigned)t, &sdead);
      {  // stage h(t) slice -> LDS
        short8v v[8];
        #pragma unroll
        for (int i = 0; i < 8; ++i) {
          int c = tid + (i << 8);
          int half = c >> 10, rem = c & 1023;
          int r = rem >> 6, col16 = rem & 63;
          const u16* p = cur + (half << 15) + ((s16 + r) << 9) + (col16 << 3);
          asm volatile("global_load_dwordx4 %0, %1, off sc0 sc1" : "=v"(v[i]) : "v"(p));
        }
        asm volatile("s_waitcnt vmcnt(0)" ::: "memory");
        __builtin_amdgcn_sched_barrier(0);
        #pragma unroll
        for (int i = 0; i < 8; ++i) {
          int c = tid + (i << 8);
          int half = c >> 10, rem = c & 1023;
          int r = rem >> 6, col16 = rem & 63;
          *(short8v*)(smem + ((half << 14) | (r << 10) | ((col16 << 4) ^ ((r & 7) << 4)))) = v[i];
        }
        __syncthreads();
      }
      float gzv, grv, ghv;
      {
        size_t rg = (size_t)((b << 6) + t) * G3_ + jg;
        gzv = gxd[rg]; grv = gxd[rg + 512]; ghv = gxd[rg + 1024];
      }
      int hoff = (bl << 10) | ((jg << 1) ^ ((bl & 7) << 4));
      float hold = bf2f(*(const u16*)(smem + hoff)) + bf2f(*(const u16*)(smem + 16384 + hoff));
      if (wv < 3) {
        float4v acc = zf;
        #pragma unroll
        for (int kt = 0; kt < 16; ++kt) {
          int aoff = (lm << 10) | (((kt << 6) + (lq << 4)) ^ ((lm & 7) << 4));
          short8v ah = *(const short8v*)(smem + aoff);
          short8v al = *(const short8v*)(smem + 16384 + aoff);
          acc = mfma16(ah, wfh[kt], acc);
          acc = mfma16(al, wfh[kt], acc);
          acc = mfma16(ah, wfl[kt], acc);
        }
        #pragma unroll
        for (int i = 0; i < 4; ++i) rec_s[wv][(lq << 2) + i][lm] = acc[i];
      }
      __syncthreads();
      wait_flag(bars, DP_F, (unsigned)(t + 1), &sdead);
      {  // batched sc loads of attention partials for this (b, jg)
        const float* p0 = pnum + (size_t)(b << 1) * G3_ + jg;
        const float* p1 = p0 + G3_;
        float pv0, pv1, pv2, pv3, pv4, pv5, d0, d1;
        asm volatile("global_load_dword %0, %1, off sc0 sc1" : "=v"(pv0) : "v"(p0));
        asm volatile("global_load_dword %0, %1, off sc0 sc1" : "=v"(pv1) : "v"(p0 + 512));
        asm volatile("global_load_dword %0, %1, off sc0 sc1" : "=v"(pv2) : "v"(p0 + 1024));
        asm volatile("global_load_dword %0, %1, off sc0 sc1" : "=v"(pv3) : "v"(p1));
        asm volatile("global_load_dword %0, %1, off sc0 sc1" : "=v"(pv4) : "v"(p1 + 512));
        asm volatile("global_load_dword %0, %1, off sc0 sc1" : "=v"(pv5) : "v"(p1 + 1024));
        asm volatile("global_load_dword %0, %1, off sc0 sc1" : "=v"(d0) : "v"(pden + (b << 1)));
        asm volatile("global_load_dword %0, %1, off sc0 sc1" : "=v"(d1) : "v"(pden + (b << 1) + 1));
        asm volatile("s_waitcnt vmcnt(0)" ::: "memory");
        __builtin_amdgcn_sched_barrier(0);
        float inv = 1.f / (d0 + d1);
        float z  = sigm(gzv + (pv0 + pv3) * inv + rec_s[0][bl][jx]);
        float r  = sigm(grv + (pv1 + pv4) * inv + rec_s[1][bl][jx]);
        float hh = tanhf(ghv + (pv2 + pv5) * inv + r * rec_s[2][bl][jx]);
        float hnew = z * hold + (1.f - z) * hh;
        u16 nh = f2bf(hnew);
        outs[(size_t)((b << 6) + t) * 512 + jg] = nh;
        if (t < TD_ - 1) {
          u16* hnx = hb + ((t & 1) ? 0 : 65536);
          st2_sc(hnx + (b << 9) + jg, nh);
          st2_sc(hnx + 32768 + (b << 9) + jg, f2bf(hnew - bf2f(nh)));
        }
      }
      if (t < TD_ - 1)
        block_arrive(bars, DH_G, set, DH_T, DH_F, 4u, (unsigned)(t + 1));
    } else {
      if (t) wait_flag(bars, DH_F, (unsigned)t, &sdead);
      if (tid < 128) {  // stage h(t)[batt] hi+lo -> LDS via sc loads
        int half = tid >> 6, cc = tid & 63;
        short8v hv = ld16_sc(cur + (half << 15) + (batt << 9) + (cc << 3));
        *(short8v*)&shs[half][cc << 3] = hv;
      }
      __syncthreads();
      { // scores: 2-way k-split dot(E~[b, t'=cset*128+tt], h[b])
        int tt = tid >> 1, kq = tid & 1;
        const u16* ep = att + (size_t)((batt << 8) + (cset << 7) + tt) * 512 + (kq << 8);
        float s = 0.f;
        #pragma unroll 4
        for (int k8 = 0; k8 < 32; ++k8) {
          short8v ev = *(const short8v*)(ep + (k8 << 3));
          short8v xh = *(const short8v*)&shs[0][(kq << 8) + (k8 << 3)];
          short8v xl = *(const short8v*)&shs[1][(kq << 8) + (k8 << 3)];
          #pragma unroll
          for (int i = 0; i < 8; ++i)
            s += bf2f((u16)ev[i]) * (bf2f((u16)xh[i]) + bf2f((u16)xl[i]));
        }
        ps[tt][kq] = s;
      }
      __syncthreads();
      if (tid < 128) {  // scores are small; exp without max is safe
        float e = expf(ps[tid][0] + ps[tid][1]);
        es[tid] = e;
        #pragma unroll
        for (int off = 32; off; off >>= 1) e += __shfl_down(e, off);
        if ((tid & 63) == 0) wsum[tid >> 6] = e;
      }
      __syncthreads();
      if (tid == 0) st4_sc(&pden[(batt << 1) + cset], wsum[0] + wsum[1]);
      { // partial softmax-weighted sums over E~2 columns (6 cols/thread)
        int c0 = tid * 6;
        float a0=0.f,a1=0.f,a2=0.f,a3=0.f,a4=0.f,a5=0.f;
        const u16* base = e2 + (size_t)((batt << 8) + (cset << 7)) * G3_ + c0;
        for (int tt = 0; tt < 128; ++tt) {
          float ev = es[tt];
          const u16* p = base + (size_t)tt * G3_;
          a0 += ev * bf2f(p[0]); a1 += ev * bf2f(p[1]); a2 += ev * bf2f(p[2]);
          a3 += ev * bf2f(p[3]); a4 += ev * bf2f(p[4]); a5 += ev * bf2f(p[5]);
        }
        float* pn = pnum + (size_t)((batt << 1) + cset) * G3_ + c0;
        float2 v01 = {a0, a1}, v23 = {a2, a3}, v45 = {a4, a5};
        st8_sc(pn, v01); st8_sc(pn + 2, v23); st8_sc(pn + 4, v45);
      }
      block_arrive(bars, DP_G, ab >> 5, DP_T, DP_F, 4u, (unsigned)(t + 1));
    }
  }
}

extern "C" void kernel_launch(void* const* d_in, const int* in_sizes, int n_in,
                              void* d_out, int out_size, void* d_ws, size_t ws_size,
                              hipStream_t stream) {
  const int*   src_seq = (const int*)d_in[0];
  const int*   dec_seq = (const int*)d_in[1];
  const float* emb     = (const float*)d_in[2];
  const float* enc_Wx  = (const float*)d_in[3];
  const float* enc_Wh  = (const float*)d_in[4];
  const float* enc_b   = (const float*)d_in[5];
  const float* dec_Wx  = (const float*)d_in[6];
  const float* dec_Wh  = (const float*)d_in[7];
  const float* dec_b   = (const float*)d_in[8];
  const float* W_att   = (const float*)d_in[9];
  const float* Wd      = (const float*)d_in[10];
  const float* bd      = (const float*)d_in[11];

  // d_out (524,288,000 B) doubles as scratch; final projection reads ONLY ws+inputs.
  char* ob = (char*)d_out;
  float* gx_all  = (float*)(ob + 0);           // [16384][1536] f32
  float* gxd_all = (float*)(ob + 100663296);   // [4096][1536] f32
  u16* srcE_h = (u16*)(ob + 125829120);        // [16384][512]
  u16* srcE_l = (u16*)(ob + 142606336);
  u16* decE_h = (u16*)(ob + 159383552);        // [4096][512]
  u16* decE_l = (u16*)(ob + 163577856);
  u16* ehs    = (u16*)(ob + 167772160);        // enc_hs bf16 [64][256][512]
  u16* attb   = (u16*)(ob + 184549376);        // E~ = ehs@W_att^T bf16
  u16* e2b    = (u16*)(ob + 201326592);        // E~2 = ehs@dec_Wx_ctx bf16 [16384][1536]
  u16* wxT_h  = (u16*)(ob + 251658240);        // enc_Wx^T [1536][512]
  u16* wxT_l  = (u16*)(ob + 253231104);
  u16* wdxT_h = (u16*)(ob + 254803968);        // dec_Wx[:512]^T
  u16* wdxT_l = (u16*)(ob + 256376832);
  u16* wxcT   = (u16*)(ob + 257949696);        // dec_Wx[512:]^T
  u16* watt   = (u16*)(ob + 259522560);        // W_att bf16 row-major
  u16* hbuf   = (u16*)(ob + 260046848);        // h dbl-buffer hi/lo, 262,144 B

  char* wb = (char*)d_ws;
  u16* outs     = (u16*)(wb + 0);              // decoder outputs bf16 [4096][512]
  float* pnum   = (float*)(wb + 4194304);      // [128][1536]
  float* pden   = (float*)(wb + 4980736);      // [128]
  unsigned* bars = (unsigned*)(wb + 4981248);  // hierarchical counters + flags
  (void)in_sizes; (void)n_in; (void)out_size; (void)ws_size;

  hipMemsetAsync(bars, 0, 4096, stream);

  k_embed<<<4096, 256, 0, stream>>>(src_seq, emb, srcE_h, srcE_l, B_*TS_*64);
  k_embed<<<1024, 256, 0, stream>>>(dec_seq, emb, decE_h, decE_l, B_*TD_*64);
  k_transp<true ><<<dim3(24, 8), 256, 0, stream>>>(enc_Wx, G3_, wxT_h,  wxT_l,  512, G3_);
  k_transp<true ><<<dim3(24, 8), 256, 0, stream>>>(dec_Wx, G3_, wdxT_h, wdxT_l, 512, G3_);
  k_transp<false><<<dim3(24, 8), 256, 0, stream>>>(dec_Wx + (size_t)512*G3_, G3_, wxcT, nullptr, 512, G3_);
  k_cvt<<<1024, 256, 0, stream>>>(W_att, watt, 512*512);

  // gate-feeding input transforms: split-precision 3-term bf16 GEMMs
  k_gemm<true, false, true, false><<<dim3(12, 128), 256, 0, stream>>>(
      srcE_h, srcE_l, wxT_h, wxT_l, nullptr, gx_all, nullptr, enc_b, 16384, G3_, 512);
  k_gemm<true, false, true, false><<<dim3(12, 32), 256, 0, stream>>>(
      decE_h, decE_l, wdxT_h, wdxT_l, nullptr, gxd_all, nullptr, dec_b, 4096, G3_, 512);

  k_encoder<<<128, 256, 0, stream>>>(gx_all, enc_Wh, hbuf, ehs, bars);

  // attention precomputes (bf16 is plenty on the attention path)
  k_gemm<false, false, false, true><<<dim3(4, 128), 256, 0, stream>>>(
      ehs, nullptr, watt, nullptr, nullptr, nullptr, attb, nullptr, 16384, 512, 512);
  k_gemm<false, false, false, true><<<dim3(12, 128), 256, 0, stream>>>(
      ehs, nullptr, wxcT, nullptr, nullptr, nullptr, e2b, nullptr, 16384, G3_, 512);

  k_decoder<<<256, 256, 0, stream>>>(gxd_all, dec_Wh, attb, e2b, hbuf, pnum, pden, outs, bars);

  // vocab projection: A = outs (ws), B = Wd f32 [512][32000] on-the-fly, writes all of d_out
  k_gemm<false, true, true, false><<<dim3(250, 32), 256, 0, stream>>>(
      outs, nullptr, nullptr, nullptr, Wd, (float*)d_out, nullptr, bd, 4096, V_, 512);
}